// Round 1
// baseline (766.969 us; speedup 1.0000x reference)
//
#include <hip/hip_runtime.h>

// Problem constants (from reference)
#define BN   8192
#define TN   128
#define SDIM 6
#define NIV  6
#define HIDN 256
#define DTC  0.01f
// IN_DIM = 50: [ e(6) | e_dot(6) | xi(6) | mf(32) ], mf constant over t per b.

// One wave (64 lanes) per batch element b. Lane L owns hidden units
// j = u*64 + L, u = 0..3 (so layer-2 weight loads are lane-coalesced).
// Weights live in registers; mf@W1 + bias folded into per-b constant.
__global__ __launch_bounds__(256, 2)
void visco_kernel(const float* __restrict__ e,    const float* __restrict__ ed,
                  const float* __restrict__ Earr, const float* __restrict__ nuarr,
                  const float* __restrict__ We,   const float* __restrict__ be,
                  const float* __restrict__ Wn,   const float* __restrict__ bn,
                  const float* __restrict__ Wen1, const float* __restrict__ ben1,
                  const float* __restrict__ Wen2, const float* __restrict__ ben2,
                  const float* __restrict__ Wd1,  const float* __restrict__ bd1,
                  const float* __restrict__ Wd2,  const float* __restrict__ bd2,
                  float* __restrict__ out)
{
    const int lane = threadIdx.x & 63;
    const int wv   = threadIdx.x >> 6;
    const int b    = (blockIdx.x << 2) + wv;   // grid = 2048 blocks * 4 waves = 8192

    // ---- per-lane weight registers ----
    float wE[2][4][6];   // layer-1 weights for e-part   (mlp 0 = encoder, 1 = kinetics)
    float wD[2][4][6];   // layer-1 weights for e_dot-part
    float wX[2][4][6];   // layer-1 weights for xi-part
    float cst[2][4];     // bias + (mf @ W1[18:50]) folded constant
    float w2s[4];        // Wen2[j]
    float w2k[4][6];     // Wd2[j][i]

    const float Eb  = Earr[b];
    const float nub = nuarr[b];

    #pragma unroll
    for (int u = 0; u < 4; ++u) {
        const int j = (u << 6) + lane;
        #pragma unroll
        for (int k = 0; k < 6; ++k) {
            wE[0][u][k] = Wen1[(k     ) * HIDN + j];
            wD[0][u][k] = Wen1[(6  + k) * HIDN + j];
            wX[0][u][k] = Wen1[(12 + k) * HIDN + j];
            wE[1][u][k] = Wd1 [(k     ) * HIDN + j];
            wD[1][u][k] = Wd1 [(6  + k) * HIDN + j];
            wX[1][u][k] = Wd1 [(12 + k) * HIDN + j];
        }
        float c0 = ben1[j];
        float c1 = bd1[j];
        #pragma unroll
        for (int k = 0; k < 16; ++k) {           // mf[0:16] = E*We + be
            const float m = fmaf(Eb, We[k], be[k]);
            c0 = fmaf(m, Wen1[(18 + k) * HIDN + j], c0);
            c1 = fmaf(m, Wd1 [(18 + k) * HIDN + j], c1);
        }
        #pragma unroll
        for (int k = 0; k < 16; ++k) {           // mf[16:32] = nu*Wn + bn
            const float m = fmaf(nub, Wn[k], bn[k]);
            c0 = fmaf(m, Wen1[(34 + k) * HIDN + j], c0);
            c1 = fmaf(m, Wd1 [(34 + k) * HIDN + j], c1);
        }
        cst[0][u] = c0;
        cst[1][u] = c1;
        w2s[u] = Wen2[j];
        #pragma unroll
        for (int i = 0; i < 6; ++i) w2k[u][i] = Wd2[j * 6 + i];
    }

    const float ben2v = ben2[0];
    float bd2v[6];
    #pragma unroll
    for (int i = 0; i < 6; ++i) bd2v[i] = bd2[i];

    // ---- state + streams ----
    float xi0 = 0.f, xi1 = 0.f, xi2 = 0.f, xi3 = 0.f, xi4 = 0.f, xi5 = 0.f;

    const float2* ep = (const float2*)(e  + (size_t)b * (TN * 6));
    const float2* dp = (const float2*)(ed + (size_t)b * (TN * 6));
    float* outS = out + (size_t)b * TN;                            // stress [B,T]
    float* outX = out + (size_t)BN * TN + (size_t)b * (TN * 6);    // xi_all [B,T,6]

    // prefetch t=0
    float2 e0 = ep[0], e1 = ep[1], e2 = ep[2];
    float2 d0 = dp[0], d1 = dp[1], d2 = dp[2];

    for (int t = 0; t < TN; ++t) {
        const float ev0 = e0.x, ev1 = e0.y, ev2 = e1.x, ev3 = e1.y, ev4 = e2.x, ev5 = e2.y;
        const float dv0 = d0.x, dv1 = d0.y, dv2 = d1.x, dv3 = d1.y, dv4 = d2.x, dv5 = d2.y;

        // prefetch t+1 (clamped; loads are independent of the xi chain)
        const int tn = (t + 1 < TN) ? t + 1 : t;
        e0 = ep[tn * 3 + 0]; e1 = ep[tn * 3 + 1]; e2 = ep[tn * 3 + 2];
        d0 = dp[tn * 3 + 0]; d1 = dp[tn * 3 + 1]; d2 = dp[tn * 3 + 2];

        float ps  = 0.f;
        float pk0 = 0.f, pk1 = 0.f, pk2 = 0.f, pk3 = 0.f, pk4 = 0.f, pk5 = 0.f;

        #pragma unroll
        for (int u = 0; u < 4; ++u) {
            float h = cst[0][u];
            float g = cst[1][u];
            h = fmaf(ev0, wE[0][u][0], h);  g = fmaf(ev0, wE[1][u][0], g);
            h = fmaf(ev1, wE[0][u][1], h);  g = fmaf(ev1, wE[1][u][1], g);
            h = fmaf(ev2, wE[0][u][2], h);  g = fmaf(ev2, wE[1][u][2], g);
            h = fmaf(ev3, wE[0][u][3], h);  g = fmaf(ev3, wE[1][u][3], g);
            h = fmaf(ev4, wE[0][u][4], h);  g = fmaf(ev4, wE[1][u][4], g);
            h = fmaf(ev5, wE[0][u][5], h);  g = fmaf(ev5, wE[1][u][5], g);
            h = fmaf(dv0, wD[0][u][0], h);  g = fmaf(dv0, wD[1][u][0], g);
            h = fmaf(dv1, wD[0][u][1], h);  g = fmaf(dv1, wD[1][u][1], g);
            h = fmaf(dv2, wD[0][u][2], h);  g = fmaf(dv2, wD[1][u][2], g);
            h = fmaf(dv3, wD[0][u][3], h);  g = fmaf(dv3, wD[1][u][3], g);
            h = fmaf(dv4, wD[0][u][4], h);  g = fmaf(dv4, wD[1][u][4], g);
            h = fmaf(dv5, wD[0][u][5], h);  g = fmaf(dv5, wD[1][u][5], g);
            h = fmaf(xi0, wX[0][u][0], h);  g = fmaf(xi0, wX[1][u][0], g);
            h = fmaf(xi1, wX[0][u][1], h);  g = fmaf(xi1, wX[1][u][1], g);
            h = fmaf(xi2, wX[0][u][2], h);  g = fmaf(xi2, wX[1][u][2], g);
            h = fmaf(xi3, wX[0][u][3], h);  g = fmaf(xi3, wX[1][u][3], g);
            h = fmaf(xi4, wX[0][u][4], h);  g = fmaf(xi4, wX[1][u][4], g);
            h = fmaf(xi5, wX[0][u][5], h);  g = fmaf(xi5, wX[1][u][5], g);
            h = fmaxf(h, 0.f);
            g = fmaxf(g, 0.f);
            ps  = fmaf(h, w2s[u],    ps);
            pk0 = fmaf(g, w2k[u][0], pk0);
            pk1 = fmaf(g, w2k[u][1], pk1);
            pk2 = fmaf(g, w2k[u][2], pk2);
            pk3 = fmaf(g, w2k[u][3], pk3);
            pk4 = fmaf(g, w2k[u][4], pk4);
            pk5 = fmaf(g, w2k[u][5], pk5);
        }

        // 64-lane butterfly reduction of 7 values (all lanes end with totals)
        #pragma unroll
        for (int m = 1; m < 64; m <<= 1) {
            ps  += __shfl_xor(ps,  m);
            pk0 += __shfl_xor(pk0, m);
            pk1 += __shfl_xor(pk1, m);
            pk2 += __shfl_xor(pk2, m);
            pk3 += __shfl_xor(pk3, m);
            pk4 += __shfl_xor(pk4, m);
            pk5 += __shfl_xor(pk5, m);
        }

        // emit xi BEFORE update (static-index select to avoid scratch), stress
        const float xw = (lane == 0) ? xi0 :
                         (lane == 1) ? xi1 :
                         (lane == 2) ? xi2 :
                         (lane == 3) ? xi3 :
                         (lane == 4) ? xi4 : xi5;
        if (lane < 6)  outX[t * 6 + lane] = xw;
        if (lane == 6) outS[t] = ps + ben2v;

        // explicit Euler update (uniform across lanes)
        xi0 = fmaf(DTC, pk0 + bd2v[0], xi0);
        xi1 = fmaf(DTC, pk1 + bd2v[1], xi1);
        xi2 = fmaf(DTC, pk2 + bd2v[2], xi2);
        xi3 = fmaf(DTC, pk3 + bd2v[3], xi3);
        xi4 = fmaf(DTC, pk4 + bd2v[4], xi4);
        xi5 = fmaf(DTC, pk5 + bd2v[5], xi5);
    }
}

extern "C" void kernel_launch(void* const* d_in, const int* in_sizes, int n_in,
                              void* d_out, int out_size, void* d_ws, size_t ws_size,
                              hipStream_t stream) {
    const float* e    = (const float*)d_in[0];
    const float* ed   = (const float*)d_in[1];
    const float* E    = (const float*)d_in[2];
    const float* nu   = (const float*)d_in[3];
    const float* We   = (const float*)d_in[4];
    const float* be   = (const float*)d_in[5];
    const float* Wn   = (const float*)d_in[6];
    const float* bn   = (const float*)d_in[7];
    const float* Wen1 = (const float*)d_in[8];
    const float* ben1 = (const float*)d_in[9];
    const float* Wen2 = (const float*)d_in[10];
    const float* ben2 = (const float*)d_in[11];
    const float* Wd1  = (const float*)d_in[12];
    const float* bd1  = (const float*)d_in[13];
    const float* Wd2  = (const float*)d_in[14];
    const float* bd2  = (const float*)d_in[15];
    float* out = (float*)d_out;

    dim3 grid(BN / 4);   // 4 waves (4 batch elems) per 256-thread block
    dim3 block(256);
    visco_kernel<<<grid, block, 0, stream>>>(e, ed, E, nu, We, be, Wn, bn,
                                             Wen1, ben1, Wen2, ben2,
                                             Wd1, bd1, Wd2, bd2, out);
}